// Round 6
// baseline (238.412 us; speedup 1.0000x reference)
//
#include <hip/hip_runtime.h>
#include <math.h>

#define NN 256
#define LL 256
#define BB 16384

typedef __attribute__((ext_vector_type(8))) short short8;
typedef __attribute__((ext_vector_type(4))) float f32x4;

// ===========================================================================
// ws layout (bytes):
//   [0.0, 1.0 MB)  coef  (float4[65536], plane-arranged, validated r3-r5)
//   [1.0, 1.5 MB)  PA    (float2[256*256]) layers 0..127 propagated
//   [1.5, 2.0 MB)  PB    (float2[256*256]) layers 128..255
//   [2.0, 3.5 MB)  Wt    (ushort[3][512][512]) bf16x3 planes of W^T
//   [3.5, 4.0 MB)  ipt   (double2[256][128]) exp(i*theta/2) table
//   [4.0, 4.5 MB)  ept   (double2[256][128]) exp(i*phi) table
// ===========================================================================

// --------------------------------------------------------------------------
// Pass A: f64 sincos tables (the only heavy-transcendental pass).
// --------------------------------------------------------------------------
__global__ void tab_kernel(const float* __restrict__ theta,
                           const float* __restrict__ phi,
                           double2* __restrict__ ipt,
                           double2* __restrict__ ept) {
    int idx = blockIdx.x * blockDim.x + threadIdx.x;   // L*128
    if (idx >= LL * 128) return;
    double s, c;
    sincos((double)theta[idx] * 0.5, &s, &c);
    ipt[idx] = make_double2(c, s);
    sincos((double)phi[idx], &s, &c);
    ept[idx] = make_double2(c, s);
}

// --------------------------------------------------------------------------
// Pass B: coef combine — pure f64 arithmetic from tables, bit-identical to
// the validated r5 coef_kernel (sincos oddness is exact).
// --------------------------------------------------------------------------
__global__ void coef_kernel(const double2* __restrict__ ipt,
                            const double2* __restrict__ ept,
                            const float* __restrict__ gamma,
                            float4* __restrict__ coef) {
    int idx = blockIdx.x * blockDim.x + threadIdx.x;
    if (idx >= LL * NN) return;
    int l = idx >> 8, j = idx & 255;
    int u = l & 1;
    int n = (j - u) & 255;
    int m = n ^ 1;
    const double2* ip = ipt + l * 128;
    const double2* ep = ept + l * 128;

    auto ipsl = [&](int k, double& re, double& im) {
        k &= 255;
        double2 v = ip[k >> 1];
        re = v.x; im = (k & 1) ? -v.y : v.y;
    };
    double inr, ini, ipr, ipi, imr, imi;
    ipsl(n, inr, ini); ipsl(n + 1, ipr, ipi); ipsl(n - 1, imr, imi);
    double enr = 1.0, eni = 0.0;
    if (!(n & 1)) { double2 v = ep[n >> 1]; enr = v.x; eni = v.y; }
    double dr = 2.0 * inr - ipr - imr;
    double di = 2.0 * ini - ipi - imi;
    double Dre = 0.25 * (enr * dr - eni * di);
    double Dim = 0.25 * (enr * di + eni * dr);
    ipsl(m, inr, ini); ipsl(m + 1, ipr, ipi); ipsl(m - 1, imr, imi);
    int mm = (m - 1) & 255;
    double emr = 1.0, emi = 0.0;
    if (!(mm & 1)) { double2 v = ep[mm >> 1]; emr = v.x; emi = v.y; }
    double orv = 2.0 * inr + ipr + imr;
    double oiv = 2.0 * ini + ipi + imi;
    double tre = emr * orv - emi * oiv;
    double tim = emr * oiv + emi * orv;
    double Ore = -0.25 * tim;
    double Oim =  0.25 * tre;

    if (l == 0) {
        double s, c;
        sincos((double)gamma[j], &s, &c);
        double a2 = Dre * c - Dim * s, b2 = Dre * s + Dim * c;
        Dre = a2; Dim = b2;
        sincos((double)gamma[j ^ 1], &s, &c);
        a2 = Ore * c - Oim * s; b2 = Ore * s + Oim * c;
        Ore = a2; Oim = b2;
    }
    coef[l * 256 + (j & 7) * 32 + (j >> 3)] =
        make_float4((float)Dre, (float)Dim, (float)Ore, (float)Oim);
}

// Packed complex MZI update (validated rounds 3-5).
__device__ __forceinline__ float2 mzi(float2 cD, float2 cO, float2 y, float2 p) {
    float2 t;
    asm("v_pk_mul_f32 %0, %1, %2 op_sel:[1,1] op_sel_hi:[1,0] neg_lo:[1,0]"
        : "=v"(t) : "v"(cO), "v"(p));
    asm("v_pk_fma_f32 %0, %1, %2, %0 op_sel:[0,0,0] op_sel_hi:[0,1,1]"
        : "+v"(t) : "v"(cO), "v"(p));
    asm("v_pk_fma_f32 %0, %1, %2, %0 op_sel:[1,1,0] op_sel_hi:[1,0,1] neg_lo:[1,0,0]"
        : "+v"(t) : "v"(cD), "v"(y));
    asm("v_pk_fma_f32 %0, %1, %2, %0 op_sel:[0,0,0] op_sel_hi:[0,1,1]"
        : "+v"(t) : "v"(cD), "v"(y));
    return t;
}
__device__ __forceinline__ float2 D_(float4 c) { return make_float2(c.x, c.y); }
__device__ __forceinline__ float2 O_(float4 c) { return make_float2(c.z, c.w); }

// --------------------------------------------------------------------------
// Identity propagation, 2 row-pair slots per wave (4 basis rows) for ILP.
// gid in [0,128): mhalf = gid>>6 selects layer half; rows 4c+2*s2+half.
// --------------------------------------------------------------------------
__global__ __launch_bounds__(256) void prop_kernel(const float4* __restrict__ coef,
                                                   float2* __restrict__ PA,
                                                   float2* __restrict__ PB) {
    const int lane = threadIdx.x & 63;
    const int wave = threadIdx.x >> 6;
    const int l32  = lane & 31;
    const int half = lane >> 5;
    const int gid  = blockIdx.x * 4 + wave;      // 0..127
    const int mhalf = gid >> 6;
    const int c4   = (gid & 63) * 4;
    const int l0   = mhalf ? 128 : 0;
    const int idxL4 = (((lane & 32) | ((lane - 1) & 31))) << 2;
    const int idxR4 = (((lane & 32) | ((lane + 1) & 31))) << 2;

    float2 y[2][8];
#pragma unroll
    for (int s2 = 0; s2 < 2; ++s2) {
        int row = c4 + 2 * s2 + half;
#pragma unroll
        for (int j = 0; j < 8; ++j)
            y[s2][j] = make_float2((8 * l32 + j == row) ? 1.f : 0.f, 0.f);
    }

    const float4* cp = coef + l32;
    auto loadl = [&](int l, float4& c0, float4& c1, float4& c2, float4& c3,
                            float4& c4_, float4& c5, float4& c6, float4& c7) {
        const float4* p = cp + l * 256;
        c0 = p[0 * 32]; c1 = p[1 * 32]; c2 = p[2 * 32]; c3 = p[3 * 32];
        c4_ = p[4 * 32]; c5 = p[5 * 32]; c6 = p[6 * 32]; c7 = p[7 * 32];
    };

    float4 a0, a1, a2, a3, a4, a5, a6, a7;
    float4 b0, b1, b2, b3, b4, b5, b6, b7;
    loadl(l0, a0, a1, a2, a3, a4, a5, a6, a7);

#pragma unroll 1
    for (int it = 0; it < 64; ++it) {
        loadl(l0 + 2 * it + 1, b0, b1, b2, b3, b4, b5, b6, b7);
#pragma unroll
        for (int s2 = 0; s2 < 2; ++s2) {   // even layer
            float2 t0 = y[s2][0], t1 = y[s2][1], t2 = y[s2][2], t3 = y[s2][3];
            float2 t4 = y[s2][4], t5 = y[s2][5], t6 = y[s2][6], t7 = y[s2][7];
            y[s2][0] = mzi(D_(a0), O_(a0), t0, t1);
            y[s2][1] = mzi(D_(a1), O_(a1), t1, t0);
            y[s2][2] = mzi(D_(a2), O_(a2), t2, t3);
            y[s2][3] = mzi(D_(a3), O_(a3), t3, t2);
            y[s2][4] = mzi(D_(a4), O_(a4), t4, t5);
            y[s2][5] = mzi(D_(a5), O_(a5), t5, t4);
            y[s2][6] = mzi(D_(a6), O_(a6), t6, t7);
            y[s2][7] = mzi(D_(a7), O_(a7), t7, t6);
        }
        if (it < 63) loadl(l0 + 2 * it + 2, a0, a1, a2, a3, a4, a5, a6, a7);
#pragma unroll
        for (int s2 = 0; s2 < 2; ++s2) {   // odd layer
            float2 t0 = y[s2][0], t1 = y[s2][1], t2 = y[s2][2], t3 = y[s2][3];
            float2 t4 = y[s2][4], t5 = y[s2][5], t6 = y[s2][6], t7 = y[s2][7];
            float2 plo, phi2;
            plo.x  = __int_as_float(__builtin_amdgcn_ds_bpermute(idxL4, __float_as_int(t7.x)));
            plo.y  = __int_as_float(__builtin_amdgcn_ds_bpermute(idxL4, __float_as_int(t7.y)));
            phi2.x = __int_as_float(__builtin_amdgcn_ds_bpermute(idxR4, __float_as_int(t0.x)));
            phi2.y = __int_as_float(__builtin_amdgcn_ds_bpermute(idxR4, __float_as_int(t0.y)));
            y[s2][1] = mzi(D_(b1), O_(b1), t1, t2);
            y[s2][2] = mzi(D_(b2), O_(b2), t2, t1);
            y[s2][3] = mzi(D_(b3), O_(b3), t3, t4);
            y[s2][4] = mzi(D_(b4), O_(b4), t4, t3);
            y[s2][5] = mzi(D_(b5), O_(b5), t5, t6);
            y[s2][6] = mzi(D_(b6), O_(b6), t6, t5);
            y[s2][0] = mzi(D_(b0), O_(b0), t0, plo);
            y[s2][7] = mzi(D_(b7), O_(b7), t7, phi2);
        }
    }

    float2* P = mhalf ? PB : PA;
#pragma unroll
    for (int s2 = 0; s2 < 2; ++s2) {
        int row = c4 + 2 * s2 + half;
#pragma unroll
        for (int j = 0; j < 8; ++j)
            P[row * 256 + 8 * l32 + j] = y[s2][j];
    }
}

// bf16 RNE + 3-way split (validated r5).
__device__ __forceinline__ unsigned short bf16rne(float f) {
    unsigned int u2 = __float_as_uint(f);
    unsigned int r = (u2 + 0x7FFFu + ((u2 >> 16) & 1u)) >> 16;
    return (unsigned short)r;
}
__device__ __forceinline__ float bf16f(unsigned short h) {
    return __uint_as_float(((unsigned int)h) << 16);
}
__device__ __forceinline__ void split3(float v, unsigned short& h0,
                                       unsigned short& h1, unsigned short& h2) {
    h0 = bf16rne(v);        float r1 = v - bf16f(h0);
    h1 = bf16rne(r1);       float r2 = r1 - bf16f(h1);
    h2 = bf16rne(r2);
}

// --------------------------------------------------------------------------
// Fused combine + W split: Cm[i][j] = (PA*PB)[i][j] in registers (fp32 math
// identical to r5), then the 4 real-expansion W entries are split to bf16x3
// and scattered (lands in L2; Wt is 1.5 MB).
// --------------------------------------------------------------------------
__global__ __launch_bounds__(256) void combineW_kernel(const float2* __restrict__ PA,
                                                       const float2* __restrict__ PB,
                                                       unsigned short* __restrict__ Wt) {
    int i = blockIdx.x, j = threadIdx.x;
    float accr = 0.f, acci = 0.f;
#pragma unroll 8
    for (int k = 0; k < 256; ++k) {
        float2 a = PA[i * 256 + k];
        float2 b = PB[k * 256 + j];
        accr += a.x * b.x - a.y * b.y;
        acci += a.x * b.y + a.y * b.x;
    }
    unsigned short r0, r1, r2, i0, i1, i2, n0, n1, n2;
    split3(accr, r0, r1, r2);
    split3(acci, i0, i1, i2);
    split3(-acci, n0, n1, n2);
    // W[k][n] -> Wt[p][n][k]:
    // (k=i,    n=j)     = accr   (k=i,    n=j+256) = acci
    // (k=i+256,n=j)     = -acci  (k=i+256,n=j+256) = accr
    unsigned short* W0 = Wt;
    unsigned short* W1 = Wt + 262144;
    unsigned short* W2 = Wt + 524288;
    W0[j * 512 + i] = r0;           W1[j * 512 + i] = r1;           W2[j * 512 + i] = r2;
    W0[(j + 256) * 512 + i] = i0;   W1[(j + 256) * 512 + i] = i1;   W2[(j + 256) * 512 + i] = i2;
    W0[j * 512 + i + 256] = n0;     W1[j * 512 + i + 256] = n1;     W2[j * 512 + i + 256] = n2;
    W0[(j + 256) * 512 + i + 256] = r0;
    W1[(j + 256) * 512 + i + 256] = r1;
    W2[(j + 256) * 512 + i + 256] = r2;
}

// --------------------------------------------------------------------------
// Main GEMM (validated r5 math), + XCD swizzle, LDS pad 42, reg-prefetch
// software pipeline.
// --------------------------------------------------------------------------
__global__ __launch_bounds__(256, 2) void gemm_kernel(
        const float* __restrict__ x_re, const float* __restrict__ x_im,
        const unsigned short* __restrict__ Wt, float* __restrict__ out) {
    __shared__ unsigned short XL[3][128][42];
    __shared__ unsigned short WL[3][128][42];

    const int t    = threadIdx.x;
    const int lane = t & 63;
    const int wave = t >> 6;
    const int wm   = wave >> 1, wn = wave & 1;
    // XCD-chunk swizzle: all 4 n-tiles of an m-panel on one XCD, co-resident.
    const int Lb = (blockIdx.x & 7) * 64 + (blockIdx.x >> 3);
    const int mt = Lb >> 2, nt = Lb & 3;
    const int m0 = mt * 128, n0 = nt * 128;
    const int lr = lane & 15, lg = lane >> 4;

    float4 xv[4];
    uint4  wv[6];
    const int F   = t;                    // X: float4 id base; row=F>>3,g=F&7 per r
    const int Un  = t;                    // W: 16B unit id base

    auto load_tiles = [&](int ks) {
        const int k0 = ks * 32;
        const float* xsrc = (k0 < 256) ? x_re : x_im;
        const int kcol = k0 & 255;
#pragma unroll
        for (int r = 0; r < 4; ++r) {
            int Fi = r * 256 + F;
            int row = Fi >> 3, g = Fi & 7;
            xv[r] = ((const float4*)xsrc)[(m0 + row) * 64 + (kcol >> 2) + g];
        }
#pragma unroll
        for (int r = 0; r < 6; ++r) {
            int U = r * 256 + Un;
            int p = U >> 9, rem = U & 511;
            int n = rem >> 2, ku = (rem & 3) * 8;
            wv[r] = ((const uint4*)Wt)[p * 32768 + (n0 + n) * 64 + ((k0 + ku) >> 3)];
        }
    };
    auto write_tiles = [&]() {
#pragma unroll
        for (int r = 0; r < 4; ++r) {
            int Fi = r * 256 + F;
            int row = Fi >> 3, g = Fi & 7;
            float4 v = xv[r];
            unsigned short h0[4], h1[4], h2[4];
            split3(v.x, h0[0], h1[0], h2[0]);
            split3(v.y, h0[1], h1[1], h2[1]);
            split3(v.z, h0[2], h1[2], h2[2]);
            split3(v.w, h0[3], h1[3], h2[3]);
            *(ushort4*)&XL[0][row][g * 4] = make_ushort4(h0[0], h0[1], h0[2], h0[3]);
            *(ushort4*)&XL[1][row][g * 4] = make_ushort4(h1[0], h1[1], h1[2], h1[3]);
            *(ushort4*)&XL[2][row][g * 4] = make_ushort4(h2[0], h2[1], h2[2], h2[3]);
        }
#pragma unroll
        for (int r = 0; r < 6; ++r) {
            int U = r * 256 + Un;
            int p = U >> 9, rem = U & 511;
            int n = rem >> 2, ku = (rem & 3) * 8;
            *(uint4*)&WL[p][n][ku] = wv[r];
        }
    };

    f32x4 acc[4][4];
#pragma unroll
    for (int a = 0; a < 4; ++a)
#pragma unroll
        for (int b = 0; b < 4; ++b) acc[a][b] = (f32x4)0.f;

    load_tiles(0);
    write_tiles();
    __syncthreads();

#pragma unroll 1
    for (int ks = 0; ks < 16; ++ks) {
        if (ks < 15) load_tiles(ks + 1);

        short8 bfr[3][4];
#pragma unroll
        for (int p = 0; p < 3; ++p)
#pragma unroll
            for (int ni = 0; ni < 4; ++ni)
                bfr[p][ni] = *(const short8*)&WL[p][wn * 64 + ni * 16 + lr][lg * 8];
#pragma unroll
        for (int i = 0; i < 3; ++i) {
            short8 af[4];
#pragma unroll
            for (int mi = 0; mi < 4; ++mi)
                af[mi] = *(const short8*)&XL[i][wm * 64 + mi * 16 + lr][lg * 8];
#pragma unroll
            for (int jj = 0; jj < 3; ++jj) {
                if (i + jj > 2) continue;
#pragma unroll
                for (int mi = 0; mi < 4; ++mi)
#pragma unroll
                    for (int ni = 0; ni < 4; ++ni)
                        acc[mi][ni] = __builtin_amdgcn_mfma_f32_16x16x32_bf16(
                            af[mi], bfr[jj][ni], acc[mi][ni], 0, 0, 0);
            }
        }
        __syncthreads();
        if (ks < 15) write_tiles();
        __syncthreads();
    }

    // epilogue (validated r5)
#pragma unroll
    for (int mi = 0; mi < 4; ++mi) {
#pragma unroll
        for (int ni = 0; ni < 4; ++ni) {
            int nglob = n0 + wn * 64 + ni * 16 + lr;
            float* dst = (nglob < 256)
                       ? out + (size_t)nglob
                       : out + (size_t)BB * 256 + (nglob - 256);
#pragma unroll
            for (int e = 0; e < 4; ++e) {
                int m = m0 + wm * 64 + mi * 16 + lg * 4 + e;
                dst[(size_t)m * 256] = acc[mi][ni][e];
            }
        }
    }
}

extern "C" void kernel_launch(void* const* d_in, const int* in_sizes, int n_in,
                              void* d_out, int out_size, void* d_ws, size_t ws_size,
                              hipStream_t stream) {
    const float* x_re  = (const float*)d_in[0];
    const float* x_im  = (const float*)d_in[1];
    const float* theta = (const float*)d_in[2];
    const float* phi   = (const float*)d_in[3];
    const float* gamma = (const float*)d_in[4];

    char* ws = (char*)d_ws;
    float4* coef        = (float4*)ws;                                   // 1 MB
    float2* PA          = (float2*)(ws + (1 << 20));                     // 512 KB
    float2* PB          = (float2*)(ws + (1 << 20) + (512 << 10));       // 512 KB
    unsigned short* Wt  = (unsigned short*)(ws + (2 << 20));             // 1.5 MB
    double2* ipt        = (double2*)(ws + (3 << 20) + (512 << 10));      // 512 KB
    double2* ept        = (double2*)(ws + (4 << 20));                    // 512 KB

    hipLaunchKernelGGL(tab_kernel, dim3(128), dim3(256), 0, stream,
                       theta, phi, ipt, ept);
    hipLaunchKernelGGL(coef_kernel, dim3(256), dim3(256), 0, stream,
                       ipt, ept, gamma, coef);
    hipLaunchKernelGGL(prop_kernel, dim3(32), dim3(256), 0, stream, coef, PA, PB);
    hipLaunchKernelGGL(combineW_kernel, dim3(256), dim3(256), 0, stream, PA, PB, Wt);
    hipLaunchKernelGGL(gemm_kernel, dim3(512), dim3(256), 0, stream,
                       x_re, x_im, Wt, (float*)d_out);
}

// Round 7
// 198.768 us; speedup vs baseline: 1.1994x; 1.1994x over previous
//
#include <hip/hip_runtime.h>
#include <math.h>

#define NN 256
#define LL 256
#define BB 16384

typedef __attribute__((ext_vector_type(8))) short short8;
typedef __attribute__((ext_vector_type(4))) float f32x4;

// ===========================================================================
// ws layout (bytes):
//   [0.0, 1.0 MB)  coef  (float4[65536], plane-arranged, validated r3-r6)
//   [1.0, 1.5 MB)  PA    (float2[256*256]) layers 0..127 propagated
//   [1.5, 2.0 MB)  PB    (float2[256*256]) layers 128..255
//   [2.0, 3.5 MB)  Wt    (ushort[3][512][512]) bf16x3 planes of W^T
// ===========================================================================

// --------------------------------------------------------------------------
// Fused coef kernel: one block per layer l.  Threads 0..127 build the f64
// sincos tables for this layer in LDS; all 256 threads then combine (pure
// f64 arithmetic, bit-identical to the r5/r6 validated coef math).
// --------------------------------------------------------------------------
__global__ __launch_bounds__(256) void coefF_kernel(const float* __restrict__ theta,
                                                    const float* __restrict__ phi,
                                                    const float* __restrict__ gamma,
                                                    float4* __restrict__ coef) {
    __shared__ double ipc[128], ips[128], epc[128], eps[128];
    const int l = blockIdx.x;
    const int t = threadIdx.x;
    if (t < 128) {
        double s, c;
        sincos((double)theta[l * 128 + t] * 0.5, &s, &c); ipc[t] = c; ips[t] = s;
        sincos((double)phi[l * 128 + t], &s, &c);         epc[t] = c; eps[t] = s;
    }
    __syncthreads();

    const int j = t;
    const int u = l & 1;
    const int n = (j - u) & 255;
    const int m = n ^ 1;

    auto ipsl = [&](int k, double& re, double& im) {
        k &= 255;
        re = ipc[k >> 1];
        im = (k & 1) ? -ips[k >> 1] : ips[k >> 1];
    };
    double inr, ini, ipr, ipi, imr, imi;
    ipsl(n, inr, ini); ipsl(n + 1, ipr, ipi); ipsl(n - 1, imr, imi);
    double enr = 1.0, eni = 0.0;
    if (!(n & 1)) { enr = epc[n >> 1]; eni = eps[n >> 1]; }
    double dr = 2.0 * inr - ipr - imr;
    double di = 2.0 * ini - ipi - imi;
    double Dre = 0.25 * (enr * dr - eni * di);
    double Dim = 0.25 * (enr * di + eni * dr);
    ipsl(m, inr, ini); ipsl(m + 1, ipr, ipi); ipsl(m - 1, imr, imi);
    int mm = (m - 1) & 255;
    double emr = 1.0, emi = 0.0;
    if (!(mm & 1)) { emr = epc[mm >> 1]; emi = eps[mm >> 1]; }
    double orv = 2.0 * inr + ipr + imr;
    double oiv = 2.0 * ini + ipi + imi;
    double tre = emr * orv - emi * oiv;
    double tim = emr * oiv + emi * orv;
    double Ore = -0.25 * tim;
    double Oim =  0.25 * tre;

    if (l == 0) {
        double s, c;
        sincos((double)gamma[j], &s, &c);
        double a2 = Dre * c - Dim * s, b2 = Dre * s + Dim * c;
        Dre = a2; Dim = b2;
        sincos((double)gamma[j ^ 1], &s, &c);
        a2 = Ore * c - Oim * s; b2 = Ore * s + Oim * c;
        Ore = a2; Oim = b2;
    }
    coef[l * 256 + (j & 7) * 32 + (j >> 3)] =
        make_float4((float)Dre, (float)Dim, (float)Ore, (float)Oim);
}

// Packed complex MZI update (validated rounds 3-6).
__device__ __forceinline__ float2 mzi(float2 cD, float2 cO, float2 y, float2 p) {
    float2 t;
    asm("v_pk_mul_f32 %0, %1, %2 op_sel:[1,1] op_sel_hi:[1,0] neg_lo:[1,0]"
        : "=v"(t) : "v"(cO), "v"(p));
    asm("v_pk_fma_f32 %0, %1, %2, %0 op_sel:[0,0,0] op_sel_hi:[0,1,1]"
        : "+v"(t) : "v"(cO), "v"(p));
    asm("v_pk_fma_f32 %0, %1, %2, %0 op_sel:[1,1,0] op_sel_hi:[1,0,1] neg_lo:[1,0,0]"
        : "+v"(t) : "v"(cD), "v"(y));
    asm("v_pk_fma_f32 %0, %1, %2, %0 op_sel:[0,0,0] op_sel_hi:[0,1,1]"
        : "+v"(t) : "v"(cD), "v"(y));
    return t;
}
__device__ __forceinline__ float2 D_(float4 c) { return make_float2(c.x, c.y); }
__device__ __forceinline__ float2 O_(float4 c) { return make_float2(c.z, c.w); }

// --------------------------------------------------------------------------
// Identity propagation, 2 row-pair slots per wave (validated r6 variant).
// --------------------------------------------------------------------------
__global__ __launch_bounds__(256) void prop_kernel(const float4* __restrict__ coef,
                                                   float2* __restrict__ PA,
                                                   float2* __restrict__ PB) {
    const int lane = threadIdx.x & 63;
    const int wave = threadIdx.x >> 6;
    const int l32  = lane & 31;
    const int half = lane >> 5;
    const int gid  = blockIdx.x * 4 + wave;      // 0..127
    const int mhalf = gid >> 6;
    const int c4   = (gid & 63) * 4;
    const int l0   = mhalf ? 128 : 0;
    const int idxL4 = (((lane & 32) | ((lane - 1) & 31))) << 2;
    const int idxR4 = (((lane & 32) | ((lane + 1) & 31))) << 2;

    float2 y[2][8];
#pragma unroll
    for (int s2 = 0; s2 < 2; ++s2) {
        int row = c4 + 2 * s2 + half;
#pragma unroll
        for (int j = 0; j < 8; ++j)
            y[s2][j] = make_float2((8 * l32 + j == row) ? 1.f : 0.f, 0.f);
    }

    const float4* cp = coef + l32;
    auto loadl = [&](int l, float4& c0, float4& c1, float4& c2, float4& c3,
                            float4& c4_, float4& c5, float4& c6, float4& c7) {
        const float4* p = cp + l * 256;
        c0 = p[0 * 32]; c1 = p[1 * 32]; c2 = p[2 * 32]; c3 = p[3 * 32];
        c4_ = p[4 * 32]; c5 = p[5 * 32]; c6 = p[6 * 32]; c7 = p[7 * 32];
    };

    float4 a0, a1, a2, a3, a4, a5, a6, a7;
    float4 b0, b1, b2, b3, b4, b5, b6, b7;
    loadl(l0, a0, a1, a2, a3, a4, a5, a6, a7);

#pragma unroll 1
    for (int it = 0; it < 64; ++it) {
        loadl(l0 + 2 * it + 1, b0, b1, b2, b3, b4, b5, b6, b7);
#pragma unroll
        for (int s2 = 0; s2 < 2; ++s2) {   // even layer
            float2 t0 = y[s2][0], t1 = y[s2][1], t2 = y[s2][2], t3 = y[s2][3];
            float2 t4 = y[s2][4], t5 = y[s2][5], t6 = y[s2][6], t7 = y[s2][7];
            y[s2][0] = mzi(D_(a0), O_(a0), t0, t1);
            y[s2][1] = mzi(D_(a1), O_(a1), t1, t0);
            y[s2][2] = mzi(D_(a2), O_(a2), t2, t3);
            y[s2][3] = mzi(D_(a3), O_(a3), t3, t2);
            y[s2][4] = mzi(D_(a4), O_(a4), t4, t5);
            y[s2][5] = mzi(D_(a5), O_(a5), t5, t4);
            y[s2][6] = mzi(D_(a6), O_(a6), t6, t7);
            y[s2][7] = mzi(D_(a7), O_(a7), t7, t6);
        }
        if (it < 63) loadl(l0 + 2 * it + 2, a0, a1, a2, a3, a4, a5, a6, a7);
#pragma unroll
        for (int s2 = 0; s2 < 2; ++s2) {   // odd layer
            float2 t0 = y[s2][0], t1 = y[s2][1], t2 = y[s2][2], t3 = y[s2][3];
            float2 t4 = y[s2][4], t5 = y[s2][5], t6 = y[s2][6], t7 = y[s2][7];
            float2 plo, phi2;
            plo.x  = __int_as_float(__builtin_amdgcn_ds_bpermute(idxL4, __float_as_int(t7.x)));
            plo.y  = __int_as_float(__builtin_amdgcn_ds_bpermute(idxL4, __float_as_int(t7.y)));
            phi2.x = __int_as_float(__builtin_amdgcn_ds_bpermute(idxR4, __float_as_int(t0.x)));
            phi2.y = __int_as_float(__builtin_amdgcn_ds_bpermute(idxR4, __float_as_int(t0.y)));
            y[s2][1] = mzi(D_(b1), O_(b1), t1, t2);
            y[s2][2] = mzi(D_(b2), O_(b2), t2, t1);
            y[s2][3] = mzi(D_(b3), O_(b3), t3, t4);
            y[s2][4] = mzi(D_(b4), O_(b4), t4, t3);
            y[s2][5] = mzi(D_(b5), O_(b5), t5, t6);
            y[s2][6] = mzi(D_(b6), O_(b6), t6, t5);
            y[s2][0] = mzi(D_(b0), O_(b0), t0, plo);
            y[s2][7] = mzi(D_(b7), O_(b7), t7, phi2);
        }
    }

    float2* P = mhalf ? PB : PA;
#pragma unroll
    for (int s2 = 0; s2 < 2; ++s2) {
        int row = c4 + 2 * s2 + half;
#pragma unroll
        for (int j = 0; j < 8; ++j)
            P[row * 256 + 8 * l32 + j] = y[s2][j];
    }
}

// bf16 RNE + 3-way split (validated r5/r6).
__device__ __forceinline__ unsigned short bf16rne(float f) {
    unsigned int u2 = __float_as_uint(f);
    unsigned int r = (u2 + 0x7FFFu + ((u2 >> 16) & 1u)) >> 16;
    return (unsigned short)r;
}
__device__ __forceinline__ float bf16f(unsigned short h) {
    return __uint_as_float(((unsigned int)h) << 16);
}
__device__ __forceinline__ void split3(float v, unsigned short& h0,
                                       unsigned short& h1, unsigned short& h2) {
    h0 = bf16rne(v);        float r1 = v - bf16f(h0);
    h1 = bf16rne(r1);       float r2 = r1 - bf16f(h1);
    h2 = bf16rne(r2);
}

// --------------------------------------------------------------------------
// Fused combine + W split (validated r6): Cm in registers, bf16x3 scatter.
// --------------------------------------------------------------------------
__global__ __launch_bounds__(256) void combineW_kernel(const float2* __restrict__ PA,
                                                       const float2* __restrict__ PB,
                                                       unsigned short* __restrict__ Wt) {
    int i = blockIdx.x, j = threadIdx.x;
    float accr = 0.f, acci = 0.f;
#pragma unroll 8
    for (int k = 0; k < 256; ++k) {
        float2 a = PA[i * 256 + k];
        float2 b = PB[k * 256 + j];
        accr += a.x * b.x - a.y * b.y;
        acci += a.x * b.y + a.y * b.x;
    }
    unsigned short r0, r1, r2, i0, i1, i2, n0, n1, n2;
    split3(accr, r0, r1, r2);
    split3(acci, i0, i1, i2);
    split3(-acci, n0, n1, n2);
    unsigned short* W0 = Wt;
    unsigned short* W1 = Wt + 262144;
    unsigned short* W2 = Wt + 524288;
    W0[j * 512 + i] = r0;           W1[j * 512 + i] = r1;           W2[j * 512 + i] = r2;
    W0[(j + 256) * 512 + i] = i0;   W1[(j + 256) * 512 + i] = i1;   W2[(j + 256) * 512 + i] = i2;
    W0[j * 512 + i + 256] = n0;     W1[j * 512 + i + 256] = n1;     W2[j * 512 + i + 256] = n2;
    W0[(j + 256) * 512 + i + 256] = r0;
    W1[(j + 256) * 512 + i + 256] = r1;
    W2[(j + 256) * 512 + i + 256] = r2;
}

// --------------------------------------------------------------------------
// Main GEMM — EXACT r5 structure (62 µs verified): stride-40 LDS, linear
// block mapping, single-stage staging, one compute phase per K-step.
// --------------------------------------------------------------------------
__global__ __launch_bounds__(256, 2) void gemm_kernel(
        const float* __restrict__ x_re, const float* __restrict__ x_im,
        const unsigned short* __restrict__ Wt, float* __restrict__ out) {
    __shared__ unsigned short XL[3][128][40];
    __shared__ unsigned short WL[3][128][40];

    const int t    = threadIdx.x;
    const int lane = t & 63;
    const int wave = t >> 6;
    const int wm   = wave >> 1, wn = wave & 1;
    const int nt = blockIdx.x & 3, mt = blockIdx.x >> 2;
    const int m0 = mt * 128, n0 = nt * 128;
    const int lr = lane & 15, lg = lane >> 4;

    f32x4 acc[4][4];
#pragma unroll
    for (int a = 0; a < 4; ++a)
#pragma unroll
        for (int b = 0; b < 4; ++b) acc[a][b] = (f32x4)0.f;

#pragma unroll 1
    for (int ks = 0; ks < 16; ++ks) {
        const int k0 = ks * 32;
        const float* xsrc = (k0 < 256) ? x_re : x_im;
        const int kcol = k0 & 255;
#pragma unroll
        for (int r = 0; r < 4; ++r) {
            int F = r * 256 + t;
            int row = F >> 3, g = F & 7;
            float4 v = ((const float4*)xsrc)[(m0 + row) * 64 + (kcol >> 2) + g];
            unsigned short h0[4], h1[4], h2[4];
            split3(v.x, h0[0], h1[0], h2[0]);
            split3(v.y, h0[1], h1[1], h2[1]);
            split3(v.z, h0[2], h1[2], h2[2]);
            split3(v.w, h0[3], h1[3], h2[3]);
            *(ushort4*)&XL[0][row][g * 4] = make_ushort4(h0[0], h0[1], h0[2], h0[3]);
            *(ushort4*)&XL[1][row][g * 4] = make_ushort4(h1[0], h1[1], h1[2], h1[3]);
            *(ushort4*)&XL[2][row][g * 4] = make_ushort4(h2[0], h2[1], h2[2], h2[3]);
        }
#pragma unroll
        for (int r = 0; r < 6; ++r) {
            int U = r * 256 + t;
            int p = U >> 9, rem = U & 511;
            int n = rem >> 2, ku = (rem & 3) * 8;
            uint4 v = ((const uint4*)Wt)[p * 32768 + (n0 + n) * 64 + ((k0 + ku) >> 3)];
            *(uint4*)&WL[p][n][ku] = v;
        }
        __syncthreads();

        short8 bfr[3][4];
#pragma unroll
        for (int p = 0; p < 3; ++p)
#pragma unroll
            for (int ni = 0; ni < 4; ++ni)
                bfr[p][ni] = *(const short8*)&WL[p][wn * 64 + ni * 16 + lr][lg * 8];

#pragma unroll
        for (int i = 0; i < 3; ++i) {
            short8 af[4];
#pragma unroll
            for (int mi = 0; mi < 4; ++mi)
                af[mi] = *(const short8*)&XL[i][wm * 64 + mi * 16 + lr][lg * 8];
#pragma unroll
            for (int jj = 0; jj < 3; ++jj) {
                if (i + jj > 2) continue;
#pragma unroll
                for (int mi = 0; mi < 4; ++mi)
#pragma unroll
                    for (int ni = 0; ni < 4; ++ni)
                        acc[mi][ni] = __builtin_amdgcn_mfma_f32_16x16x32_bf16(
                            af[mi], bfr[jj][ni], acc[mi][ni], 0, 0, 0);
            }
        }
        __syncthreads();
    }

#pragma unroll
    for (int mi = 0; mi < 4; ++mi) {
#pragma unroll
        for (int ni = 0; ni < 4; ++ni) {
            int nglob = n0 + wn * 64 + ni * 16 + lr;
            float* dst = (nglob < 256)
                       ? out + (size_t)nglob
                       : out + (size_t)BB * 256 + (nglob - 256);
#pragma unroll
            for (int e = 0; e < 4; ++e) {
                int m = m0 + wm * 64 + mi * 16 + lg * 4 + e;
                dst[(size_t)m * 256] = acc[mi][ni][e];
            }
        }
    }
}

extern "C" void kernel_launch(void* const* d_in, const int* in_sizes, int n_in,
                              void* d_out, int out_size, void* d_ws, size_t ws_size,
                              hipStream_t stream) {
    const float* x_re  = (const float*)d_in[0];
    const float* x_im  = (const float*)d_in[1];
    const float* theta = (const float*)d_in[2];
    const float* phi   = (const float*)d_in[3];
    const float* gamma = (const float*)d_in[4];

    char* ws = (char*)d_ws;
    float4* coef        = (float4*)ws;                                   // 1 MB
    float2* PA          = (float2*)(ws + (1 << 20));                     // 512 KB
    float2* PB          = (float2*)(ws + (1 << 20) + (512 << 10));       // 512 KB
    unsigned short* Wt  = (unsigned short*)(ws + (2 << 20));             // 1.5 MB

    hipLaunchKernelGGL(coefF_kernel, dim3(256), dim3(256), 0, stream,
                       theta, phi, gamma, coef);
    hipLaunchKernelGGL(prop_kernel, dim3(32), dim3(256), 0, stream, coef, PA, PB);
    hipLaunchKernelGGL(combineW_kernel, dim3(256), dim3(256), 0, stream, PA, PB, Wt);
    hipLaunchKernelGGL(gemm_kernel, dim3(512), dim3(256), 0, stream,
                       x_re, x_im, Wt, (float*)d_out);
}